// Round 15
// baseline (266.014 us; speedup 1.0000x reference)
//
#include <hip/hip_runtime.h>

typedef float    f32x4 __attribute__((ext_vector_type(4)));
typedef _Float16 f16x8 __attribute__((ext_vector_type(8)));
typedef _Float16 f16x4 __attribute__((ext_vector_type(4)));

// async global->LDS, 16B per lane (dest = wave-uniform base + lane*16)
__device__ __forceinline__ void gload16(const void* g, void* l) {
  __builtin_amdgcn_global_load_lds(
      (__attribute__((address_space(1))) void*)(const void*)g,
      (__attribute__((address_space(3))) void*)l,
      16, 0, 0);
}

// coalesced f16 tile flush: LDS bounce region (8 wave regions x 4096 f16,
// row-major [64][64] with col XOR) -> global [128][256] tile.
__device__ __forceinline__ void bounce_flush(const _Float16* lds, _Float16* gbase,
                                             int ldo, int t) {
#pragma unroll
  for (int it = 0; it < 8; ++it) {
    const int s = t + it * 512;
    const int R = s >> 5;            // tile row 0..127
    const int C = (s & 31) * 8;      // tile col 0..248
    const int wsrc = ((R >> 6) << 2) | (C >> 6);
    const f16x8 v = *(const f16x8*)(lds + wsrc * 4096 + (R & 63) * 64 +
                                    ((C & 63) ^ ((R & 12) << 2)));
    *(f16x8*)(gbase + (size_t)R * ldo + C) = v;
  }
}

// ================== 128x256 BT-GEMM engine (proj/PV/FFN) ==================
// (round-14 proven; unchanged)
// EPI 0: out1(f16) = acc + bias[col]; EPI 3: out0(f32)=residh+relu(acc);
// EPI 6: fused PV (cv from LDS c-table), out1(f16) = acc + resid(f32)
template <int EPI>
__global__ __launch_bounds__(512, 4) void gemm_kt(
    const _Float16* __restrict__ A, size_t sA, int lda,
    const _Float16* __restrict__ B, size_t sB, int ldb,
    float* __restrict__ out0, _Float16* __restrict__ out1,
    size_t sO, int ldo,
    const float* __restrict__ bias,
    const float* __restrict__ resid,
    const _Float16* __restrict__ residh,
    const _Float16* __restrict__ cf,
    int K) {
  __shared__ _Float16 lds[3 * 12288];              // 73728 B; reused as bounce
  __shared__ _Float16 clds[(EPI == 6) ? 4096 : 1]; // EPI6: [2 chunks][2048]

  const int gx = gridDim.x, gy = gridDim.y;
  const int nblk = gx * gy * gridDim.z;
  int lin = (blockIdx.z * gy + blockIdx.y) * gx + blockIdx.x;
  lin = (lin & 7) * (nblk >> 3) + (lin >> 3);
  const int b  = lin / (gx * gy);
  const int r2 = lin - b * gx * gy;
  const int m0 = (r2 / gx) * 128;
  const int n0 = (r2 - (r2 / gx) * gx) * 256;

  const int t = threadIdx.x, lane = t & 63, w = t >> 6;
  const int wr = w >> 2, wc = w & 3;
  const int lr = lane & 15, lq = lane >> 4;

  const _Float16* Ab = A + (size_t)b * sA;
  const _Float16* Bb = B + (size_t)b * sB;

  const int arow = t >> 2;
  const int acol = ((t & 3) ^ ((arow >> 1) & 3)) * 8;
  const _Float16* a_src  = Ab + (size_t)(m0 + arow) * lda + acol;
  const _Float16* b_src0 = Bb + (size_t)(n0 + arow) * ldb + acol;
  const _Float16* b_src1 = b_src0 + (size_t)128 * ldb;
  const int a_dst  = t * 8;
  const int b_dst0 = 4096 + t * 8;
  const int b_dst1 = 4096 + (t + 512) * 8;

  const int swz  = ((lr >> 1) & 3) << 3;
  const int koff = (lq * 8) ^ swz;
  const int a_rd = (wr * 64 + lr) * 32 + koff;
  const int b_rd = 4096 + (wc * 64 + lr) * 32 + koff;

  f32x4 acc[4][4];
#pragma unroll
  for (int f = 0; f < 4; ++f)
#pragma unroll
    for (int j = 0; j < 4; ++j) acc[f][j] = (f32x4){0.f, 0.f, 0.f, 0.f};

  const int NT = K >> 5;

  if constexpr (EPI == 6)
    gload16(cf + ((size_t)b * 32 + (m0 >> 6)) * 2048 + t * 8, clds + t * 8);
  gload16(a_src,       lds + a_dst);
  gload16(b_src0,      lds + b_dst0);
  gload16(b_src1,      lds + b_dst1);
  gload16(a_src  + 32, lds + 12288 + a_dst);
  gload16(b_src0 + 32, lds + 12288 + b_dst0);
  gload16(b_src1 + 32, lds + 12288 + b_dst1);

  int buf = 0;
  for (int kt = 0; kt < NT; ++kt) {
    if (kt + 1 < NT) asm volatile("s_waitcnt vmcnt(3)" ::: "memory");
    else             asm volatile("s_waitcnt vmcnt(0)" ::: "memory");
    __builtin_amdgcn_s_barrier();
    __builtin_amdgcn_sched_barrier(0);

    const _Float16* lb = lds + buf * 12288;
    const int nb = (buf + 2 >= 3) ? buf - 1 : buf + 2;
    _Float16* ln = lds + nb * 12288;

    f16x8 af[4], bf[4], cv;
    if constexpr (EPI == 6)
      cv = *(const f16x8*)(clds + wr * 2048 + kt * 32 + lq * 8);
#pragma unroll
    for (int f = 0; f < 4; ++f) {
      af[f] = *(const f16x8*)(lb + a_rd + f * 512);
      if constexpr (EPI == 6) af[f] = af[f] * cv;
    }
#pragma unroll
    for (int j = 0; j < 4; ++j) bf[j] = *(const f16x8*)(lb + b_rd + j * 512);
    if (kt + 2 < NT) {
      const int ko = (kt + 2) * 32;
      gload16(a_src  + ko, ln + a_dst);
      gload16(b_src0 + ko, ln + b_dst0);
      gload16(b_src1 + ko, ln + b_dst1);
    }
    __builtin_amdgcn_s_setprio(1);
#pragma unroll
    for (int f = 0; f < 4; ++f)
#pragma unroll
      for (int j = 0; j < 4; ++j)
        acc[f][j] = __builtin_amdgcn_mfma_f32_16x16x32_f16(af[f], bf[j], acc[f][j], 0, 0, 0);
    __builtin_amdgcn_s_setprio(0);
    __builtin_amdgcn_sched_barrier(0);
    buf = (buf + 1 >= 3) ? 0 : buf + 1;
  }

  if constexpr (EPI == 0 || EPI == 6) {
    __syncthreads();
    _Float16* breg = lds + w * 4096;
#pragma unroll
    for (int f = 0; f < 4; ++f)
#pragma unroll
      for (int j = 0; j < 4; ++j) {
        const int cb = ((j ^ lq) << 4) + lr;
#pragma unroll
        for (int r = 0; r < 4; ++r) {
          float v = acc[f][j][r];
          if constexpr (EPI == 0) {
            if (bias) v += bias[n0 + wc * 64 + j * 16 + lr];
          } else {
            const int row = m0 + wr * 64 + f * 16 + lq * 4 + r;
            const int col = n0 + wc * 64 + j * 16 + lr;
            v += resid[(size_t)b * sO + (size_t)row * ldo + col];
          }
          breg[(f * 16 + lq * 4 + r) * 64 + cb] = (_Float16)v;
        }
      }
    __syncthreads();
    bounce_flush(lds, out1 + (size_t)b * sO + (size_t)m0 * ldo + n0, ldo, t);
  } else {  // EPI == 3
#pragma unroll
    for (int f = 0; f < 4; ++f)
#pragma unroll
      for (int j = 0; j < 4; ++j)
#pragma unroll
        for (int r = 0; r < 4; ++r) {
          const int row = m0 + wr * 64 + f * 16 + lq * 4 + r;
          const int col = n0 + wc * 64 + j * 16 + lr;
          const size_t oidx = (size_t)b * sO + (size_t)row * ldo + col;
          const float v = acc[f][j][r];
          out0[oidx] = (float)residh[oidx] + (v > 0.f ? v : 0.f);
        }
  }
}

// ================== 256x256 2-phase-deep E-pass ==================
// S = k q^T (M=N=2048, K=768, lda=ldb=1536). 8 waves (2Mx4N), wave 128x64,
// acc[8][4]. BK=32, 3 bufs x 32KB = 96KB (1 block/CU). Per K-tile: 2 phases
// with lockstep barriers; frags loaded one phase ahead; counted vmcnt(4).
// Epilogue: per-chunk stats (m,Z) + E' f16 via two-stage 32KB bounce.
__global__ __launch_bounds__(512, 2) void epass256(
    const _Float16* __restrict__ A, const _Float16* __restrict__ B,
    float* __restrict__ pm, float* __restrict__ pZ,
    _Float16* __restrict__ E) {
  __shared__ _Float16 lds3[3 * 16384];  // 98304 B

  const int gx = 8, gy = 8;
  const int nblk = 512;
  int lin = (blockIdx.z * gy + blockIdx.y) * gx + blockIdx.x;
  lin = (lin & 7) * (nblk >> 3) + (lin >> 3);
  const int b  = lin >> 6;
  const int r2 = lin & 63;
  const int m0 = (r2 >> 3) * 256;
  const int n0 = (r2 & 7) * 256;

  const int t = threadIdx.x, lane = t & 63, w = t >> 6;
  const int wr = w >> 2, wc = w & 3;
  const int lr = lane & 15, lq = lane >> 4;

  const _Float16* Ab = A + (size_t)b * 2048 * 1536;
  const _Float16* Bb = B + (size_t)b * 2048 * 1536;

  // staging: tile A[256][32] = 1024 segs, thread t stages segs t, t+512
  const int arow = t >> 2;
  const int acol = ((t & 3) ^ ((arow >> 1) & 3)) * 8;
  const _Float16* a_src0 = Ab + (size_t)(m0 + arow) * 1536 + acol;
  const _Float16* a_src1 = a_src0 + (size_t)128 * 1536;
  const _Float16* b_src0 = Bb + (size_t)(n0 + arow) * 1536 + acol;
  const _Float16* b_src1 = b_src0 + (size_t)128 * 1536;
  const int a_d0 = t * 8, a_d1 = (t + 512) * 8;
  const int b_d0 = 8192 + t * 8, b_d1 = 8192 + (t + 512) * 8;

  const int swz  = ((lr >> 1) & 3) << 3;
  const int koff = (lq * 8) ^ swz;
  const int a_rd = (wr * 128 + lr) * 32 + koff;          // + f*512
  const int b_rd = 8192 + (wc * 64 + lr) * 32 + koff;    // + j*512

  f32x4 acc[8][4];
#pragma unroll
  for (int f = 0; f < 8; ++f)
#pragma unroll
    for (int j = 0; j < 4; ++j) acc[f][j] = (f32x4){0.f, 0.f, 0.f, 0.f};

  const int NT = 24;  // K=768 / 32

  // prologue: stage tiles 0,1 (4 ops each)
  gload16(a_src0, lds3 + a_d0);
  gload16(a_src1, lds3 + a_d1);
  gload16(b_src0, lds3 + b_d0);
  gload16(b_src1, lds3 + b_d1);
  gload16(a_src0 + 32, lds3 + 16384 + a_d0);
  gload16(a_src1 + 32, lds3 + 16384 + a_d1);
  gload16(b_src0 + 32, lds3 + 16384 + b_d0);
  gload16(b_src1 + 32, lds3 + 16384 + b_d1);
  asm volatile("s_waitcnt vmcnt(4)" ::: "memory");  // tile 0 landed
  __builtin_amdgcn_s_barrier();
  __builtin_amdgcn_sched_barrier(0);

  f16x8 afc[4], afb[4], bfc[4], afn[4], bfn[4];
#pragma unroll
  for (int f = 0; f < 4; ++f) afc[f] = *(const f16x8*)(lds3 + a_rd + f * 512);
#pragma unroll
  for (int j = 0; j < 4; ++j) bfc[j] = *(const f16x8*)(lds3 + b_rd + j * 512);

  for (int kt = 0; kt < NT; ++kt) {
    const _Float16* lb = lds3 + (kt % 3) * 16384;
    const _Float16* lnx = lds3 + ((kt + 1) % 3) * 16384;
    _Float16* lst = lds3 + ((kt + 2) % 3) * 16384;
    const bool st2 = (kt + 2 < NT), nx = (kt + 1 < NT);
    const int ko = (kt + 2) * 32;

    // ---- phase 1: stage A(kt+2) | read af4-7(kt) | MFMA f0-3 ----
    if (st2) {
      gload16(a_src0 + ko, lst + a_d0);
      gload16(a_src1 + ko, lst + a_d1);
    }
#pragma unroll
    for (int f = 0; f < 4; ++f) afb[f] = *(const f16x8*)(lb + a_rd + (4 + f) * 512);
    __builtin_amdgcn_s_setprio(1);
#pragma unroll
    for (int f = 0; f < 4; ++f)
#pragma unroll
      for (int j = 0; j < 4; ++j)
        acc[f][j] = __builtin_amdgcn_mfma_f32_16x16x32_f16(afc[f], bfc[j], acc[f][j], 0, 0, 0);
    __builtin_amdgcn_s_setprio(0);
    asm volatile("s_waitcnt lgkmcnt(0)" ::: "memory");
    __builtin_amdgcn_s_barrier();
    __builtin_amdgcn_sched_barrier(0);

    // ---- phase 2: stage B(kt+2) | vmcnt | read next af0-3,bf0-3 | MFMA f4-7
    if (st2) {
      gload16(b_src0 + ko, lst + b_d0);
      gload16(b_src1 + ko, lst + b_d1);
    }
    if (nx) {
      if (st2) asm volatile("s_waitcnt vmcnt(4)" ::: "memory");
      else     asm volatile("s_waitcnt vmcnt(0)" ::: "memory");
      __builtin_amdgcn_sched_barrier(0);
#pragma unroll
      for (int f = 0; f < 4; ++f) afn[f] = *(const f16x8*)(lnx + a_rd + f * 512);
#pragma unroll
      for (int j = 0; j < 4; ++j) bfn[j] = *(const f16x8*)(lnx + b_rd + j * 512);
    }
    __builtin_amdgcn_s_setprio(1);
#pragma unroll
    for (int f = 0; f < 4; ++f)
#pragma unroll
      for (int j = 0; j < 4; ++j)
        acc[4 + f][j] = __builtin_amdgcn_mfma_f32_16x16x32_f16(afb[f], bfc[j], acc[4 + f][j], 0, 0, 0);
    __builtin_amdgcn_s_setprio(0);
    asm volatile("s_waitcnt lgkmcnt(0)" ::: "memory");
    __builtin_amdgcn_s_barrier();
    __builtin_amdgcn_sched_barrier(0);
    if (nx) {
#pragma unroll
      for (int f = 0; f < 4; ++f) afc[f] = afn[f];
#pragma unroll
      for (int j = 0; j < 4; ++j) bfc[j] = bfn[j];
    }
  }

  // ---- epilogue: two halves (h=0: f0-3 / h=1: f4-7), 32KB bounce each ----
  _Float16* breg = lds3 + w * 4096;
#pragma unroll
  for (int h = 0; h < 2; ++h) {
    if (h == 1) __syncthreads();  // flush(0) reads done before overwrite
#pragma unroll
    for (int j = 0; j < 4; ++j) {
      float m = -3.4e38f;
#pragma unroll
      for (int f = 0; f < 4; ++f)
#pragma unroll
        for (int r = 0; r < 4; ++r) m = fmaxf(m, acc[h * 4 + f][j][r]);
#pragma unroll
      for (int d = 16; d <= 32; d <<= 1) m = fmaxf(m, __shfl_xor(m, d, 64));
      float Z = 0.f;
      const int cb = ((j ^ lq) << 4) + lr;
#pragma unroll
      for (int f = 0; f < 4; ++f)
#pragma unroll
        for (int r = 0; r < 4; ++r) {
          const _Float16 eh = (_Float16)__expf(acc[h * 4 + f][j][r] - m);
          breg[(f * 16 + lq * 4 + r) * 64 + cb] = eh;
          Z += (float)eh;
        }
#pragma unroll
      for (int d = 16; d <= 32; d <<= 1) Z += __shfl_xor(Z, d, 64);
      if (lq == 0) {
        const int chunk = (m0 >> 6) + wr * 2 + h;
        const int col = n0 + wc * 64 + j * 16 + lr;
        const size_t sidx = ((size_t)b * 32 + chunk) * 2048 + col;
        pm[sidx] = m;
        pZ[sidx] = Z;
      }
    }
    __syncthreads();
    // flush half h: rows {wr*128 + h*64 + 0..63}
#pragma unroll
    for (int it = 0; it < 8; ++it) {
      const int s = t + it * 512;
      const int Rp = s >> 5;           // 0..127 (2 wave-halves x 64)
      const int C  = (s & 31) * 8;     // 0..248
      const int wsrc = ((Rp >> 6) << 2) | (C >> 6);
      const int rl = Rp & 63;
      const f16x8 v = *(const f16x8*)(lds3 + wsrc * 4096 + rl * 64 +
                                      ((C & 63) ^ (((rl >> 2) & 3) << 4)));
      const int grow = m0 + (Rp >> 6) * 128 + h * 64 + rl;
      *(f16x8*)(E + (size_t)b * 2048 * 2048 + (size_t)grow * 2048 + n0 + C) = v;
    }
  }
}

// ---- all weight converts + bias concat in one dispatch ----
__global__ __launch_bounds__(256) void wconv(
    const float* __restrict__ Wk, const float* __restrict__ Wq,
    const float* __restrict__ W1, const float* __restrict__ W2,
    _Float16* __restrict__ Wkqf, _Float16* __restrict__ W1f,
    _Float16* __restrict__ W2f,
    const float* __restrict__ bk, const float* __restrict__ bq,
    float* __restrict__ bkq) {
  const int by = blockIdx.y;
  const long i = (long)blockIdx.x * 256 + threadIdx.x;
  if (by == 4) {
    if (i < 768) bkq[i] = bk[i];
    else if (i < 1536) bkq[i] = bq[i - 768];
    return;
  }
  const float* in = (by == 0) ? Wk : (by == 1) ? Wq : (by == 2) ? W1 : W2;
  _Float16* outp = (by == 0) ? Wkqf : (by == 1) ? (Wkqf + 589824)
                  : (by == 2) ? W1f : W2f;
  f32x4 v0 = *(const f32x4*)(in + i * 8);
  f32x4 v1 = *(const f32x4*)(in + i * 8 + 4);
  f16x8 o;
  o[0] = (_Float16)v0[0]; o[1] = (_Float16)v0[1]; o[2] = (_Float16)v0[2]; o[3] = (_Float16)v0[3];
  o[4] = (_Float16)v1[0]; o[5] = (_Float16)v1[1]; o[6] = (_Float16)v1[2]; o[7] = (_Float16)v1[3];
  *(f16x8*)(outp + i * 8) = o;
}

// ---- combine 32 chunk partials per column -> c[b][chunk][col] (f16) ----
__global__ __launch_bounds__(256) void col_final(const float* __restrict__ pm,
                                                 const float* __restrict__ pZ,
                                                 _Float16* __restrict__ c) {
  const int b = blockIdx.z;
  const int col = blockIdx.x * 256 + threadIdx.x;
  float mv[32];
  float m = -3.4e38f;
#pragma unroll
  for (int k = 0; k < 32; ++k) {
    mv[k] = pm[((size_t)b * 32 + k) * 2048 + col];
    m = fmaxf(m, mv[k]);
  }
  float Z = 0.f;
#pragma unroll
  for (int k = 0; k < 32; ++k)
    Z += pZ[((size_t)b * 32 + k) * 2048 + col] * __expf(mv[k] - m);
  const float rZ = 1.f / Z;
#pragma unroll
  for (int k = 0; k < 32; ++k)
    c[((size_t)b * 32 + k) * 2048 + col] = (_Float16)(__expf(mv[k] - m) * rZ);
}

// ---- x[b][j][c] f32 -> xf[b][j][c] f16 AND xT[b][c][j] f16, one pass ----
__global__ void xprep(const float* __restrict__ x, _Float16* __restrict__ xf,
                      _Float16* __restrict__ xT) {
  __shared__ float tile[32][33];
  const int b = blockIdx.z;
  const int c0 = blockIdx.x * 32, j0 = blockIdx.y * 32;
  const float* xb = x + (size_t)b * 2048 * 768;
  const int tx = threadIdx.x, ty = threadIdx.y;  // 32 x 8
#pragma unroll
  for (int dy = 0; dy < 32; dy += 8)
    tile[ty + dy][tx] = xb[(size_t)(j0 + ty + dy) * 768 + c0 + tx];
  __syncthreads();
  {
    const int u = ty * 32 + tx;
    const int row = u >> 3, c4 = (u & 7) * 4;
    f16x4 o;
#pragma unroll
    for (int q = 0; q < 4; ++q) o[q] = (_Float16)tile[row][c4 + q];
    *(f16x4*)(xf + ((size_t)b * 2048 + j0 + row) * 768 + c0 + c4) = o;
  }
  _Float16* xTb = xT + (size_t)b * 768 * 2048;
#pragma unroll
  for (int dy = 0; dy < 32; dy += 8)
    xTb[(size_t)(c0 + ty + dy) * 2048 + j0 + tx] = (_Float16)tile[tx][ty + dy];
}

extern "C" void kernel_launch(void* const* d_in, const int* in_sizes, int n_in,
                              void* d_out, int out_size, void* d_ws, size_t ws_size,
                              hipStream_t stream) {
  const float* x  = (const float*)d_in[0];
  const float* Wk = (const float*)d_in[1];
  const float* bk = (const float*)d_in[2];
  const float* Wq = (const float*)d_in[3];
  const float* bq = (const float*)d_in[4];
  const float* W1 = (const float*)d_in[5];
  const float* W2 = (const float*)d_in[6];
  float* out = (float*)d_out;

  // ---- ws layout (~168 MiB peak) ----
  char* ws = (char*)d_ws;
  size_t off = 0;
  auto alloc = [&](size_t bytes) -> char* {
    char* p = ws + off;
    off += (bytes + 255) & ~(size_t)255;
    return p;
  };
  _Float16* xf = (_Float16*)alloc(25165824);
  _Float16* kq = (_Float16*)alloc(50331648);
  _Float16* Wf = (_Float16*)alloc(4718592);
  _Float16* E  = (_Float16*)alloc(67108864);
  _Float16* xT = (_Float16*)alloc(25165824);
  float*    pm = (float*)alloc(2097152);
  float*    pZ = (float*)alloc(2097152);
  float*    bkq  = (float*)alloc(6144);

  _Float16* Wkqf = Wf;
  _Float16* W1f  = Wf + 2 * 589824;
  _Float16* W2f  = Wf + 3 * 589824;
  _Float16* pf16 = kq;
  _Float16* cT   = kq + 12582912;
  _Float16* hf16 = kq + 12582912;   // overwrites cT after PV (stream order)

  const size_t sKQ = (size_t)2048 * 1536;
  const size_t sS  = (size_t)2048 * 2048;
  const size_t sKV = (size_t)2048 * 768;

  // 1. x prep + weight converts
  xprep<<<dim3(24, 64, 8), dim3(32, 8), 0, stream>>>(x, xf, xT);
  wconv<<<dim3(288, 5), 256, 0, stream>>>(Wk, Wq, W1, W2, Wkqf, W1f, W2f,
                                          bk, bq, bkq);

  // 2. merged projection: kq = x * Wkq^T + bkq  (M=16384, N=1536, K=768)
  gemm_kt<0><<<dim3(6, 128, 1), 512, 0, stream>>>(xf, 0, 768, Wkqf, 0, 768,
                                                  nullptr, kq, 0, 1536,
                                                  bkq, nullptr, nullptr, nullptr, 768);

  // 3. E pass (256^2 2-phase-deep): S = k q^T; E' + (m,Z) partials
  epass256<<<dim3(8, 8, 8), 512, 0, stream>>>(kq, kq + 768, pm, pZ, E);
  col_final<<<dim3(8, 1, 8), 256, 0, stream>>>(pm, pZ, cT);

  // 4. fused PV: p = x + (E' .* c) x  (M=2048, N=768, K=2048)
  gemm_kt<6><<<dim3(3, 16, 8), 512, 0, stream>>>(E, sS, 2048, xT, sKV, 2048,
                                                 nullptr, pf16, sKV, 768,
                                                 nullptr, x, nullptr, cT, 2048);

  // 5. FFN1: h = p * W1^T
  gemm_kt<0><<<dim3(3, 128, 1), 512, 0, stream>>>(pf16, 0, 768, W1f, 0, 768,
                                                  nullptr, hf16, 0, 768,
                                                  nullptr, nullptr, nullptr, nullptr, 768);

  // 6. FFN2 + residual + relu
  gemm_kt<3><<<dim3(3, 128, 1), 512, 0, stream>>>(hf16, 0, 768, W2f, 0, 768,
                                                  out, nullptr, 0, 768,
                                                  nullptr, nullptr, pf16, nullptr, 768);
}